// Round 12
// baseline (191.161 us; speedup 1.0000x reference)
//
#include <hip/hip_runtime.h>
#include <math.h>

typedef __attribute__((ext_vector_type(8))) short short8;
typedef __attribute__((ext_vector_type(8))) unsigned short ushort8;
typedef __attribute__((ext_vector_type(4))) float f32x4;

#define NTHR 256
#define CAP 192  // bucket capacity; max in-degree of Poisson(64) over 10k nodes ~ 110

// ---------- bf16 helpers (RNE) ----------
__device__ __forceinline__ ushort f2bf(float f) {
    uint u = __float_as_uint(f);
    return (ushort)((u + 0x7FFFu + ((u >> 16) & 1u)) >> 16);
}
__device__ __forceinline__ uint pk2bf(float a, float b) {
    return (uint)f2bf(a) | ((uint)f2bf(b) << 16);
}
__device__ __forceinline__ float bfl(uint r) { return __uint_as_float(r << 16); }
__device__ __forceinline__ float bfh(uint r) { return __uint_as_float(r & 0xFFFF0000u); }

struct Params {
    const float* x; const float* dis;
    const float* W1; const float* b1;
    const float* W2; const float* b2;
    const float* W3; const float* b3;
    const float* Wout; const float* bout;
    const int* src; const int* dst; const int* ti;
    float* out;
    uint* degOut; uint* fill;          // adjacent: one memset zeroes both
    float* normOut; float* normIn;
    ushort* ebkt;                      // [N][CAP] src ids; tail padded to x8 with id N
    ushort* xbf;                       // [N+1][128] pre-scaled by normOut; row N zeros
    ushort* w1bf; ushort* w2bf; ushort* w3bf;  // [K][N] row-major bf16
    ushort* bufA;                      // [N][256] scratch (agg outputs)
    ushort* bufB;                      // [N+1][256]
    ushort* bufC;                      // [N+1][64]
    float* av; float* bv;
    int N, E, P;
};

// ------- k_deg_scatter: edge pass (2 edges/thread) + weight bf16 cvt (indep. work) -------
__global__ __launch_bounds__(NTHR) void k_deg_scatter(Params p) {
    int gtid = blockIdx.x * NTHR + threadIdx.x;
    int e = gtid * 2;
    if (e + 1 < p.E) {
        int2 s2 = *(const int2*)&p.src[e];
        int2 d2 = *(const int2*)&p.dst[e];
        atomicAdd(&p.degOut[s2.x], 1u);
        atomicAdd(&p.degOut[s2.y], 1u);
        uint p0 = atomicAdd(&p.fill[d2.x], 1u);
        p.ebkt[(size_t)d2.x * CAP + p0] = (ushort)s2.x;
        uint p1 = atomicAdd(&p.fill[d2.y], 1u);
        p.ebkt[(size_t)d2.y * CAP + p1] = (ushort)s2.y;
    } else if (e < p.E) {
        int s = p.src[e];
        int v = p.dst[e];
        atomicAdd(&p.degOut[s], 1u);
        uint pos = atomicAdd(&p.fill[v], 1u);
        p.ebkt[(size_t)v * CAP + pos] = (ushort)s;
    }
    // weight conversions (no degree dependency) — same layout as source, coalesced
    const int n1 = 128 * 256, n2 = 256 * 256, n3 = 256 * 64;
    int GSZ = gridDim.x * NTHR;
    int nw4 = (n1 + n2 + n3) >> 2;
    for (int i4 = gtid; i4 < nw4; i4 += GSZ) {
        int i = i4 * 4;
        const float* s;
        ushort* d;
        int off;
        if (i < n1) { s = p.W1; d = p.w1bf; off = i; }
        else if (i < n1 + n2) { s = p.W2; d = p.w2bf; off = i - n1; }
        else { s = p.W3; d = p.w3bf; off = i - n1 - n2; }
        float4 v = *(const float4*)&s[off];
        uint2 pkv;
        pkv.x = pk2bf(v.x, v.y);
        pkv.y = pk2bf(v.z, v.w);
        *(uint2*)&d[off] = pkv;
    }
}

// ------- k_norm_cvt: norms, bucket tail-pad, xbf (pre-scaled), pad rows -------
__global__ __launch_bounds__(NTHR) void k_norm_cvt(Params p) {
    int gtid = blockIdx.x * NTHR + threadIdx.x;
    int GSZ = gridDim.x * NTHR;
    for (int v = gtid; v < p.N; v += GSZ) {
        uint d0 = p.degOut[v];
        uint d1 = p.fill[v];
        p.normOut[v] = d0 ? rsqrtf((float)d0) : 0.f;
        p.normIn[v] = d1 ? rsqrtf((float)d1) : 0.f;
        uint c8 = (d1 + 7) & ~7u;
        ushort* eb = p.ebkt + (size_t)v * CAP;
        for (uint j = d1; j < c8; ++j) eb[j] = (ushort)p.N;
    }
    // zero pad row N of xbf (64 uints), bufB (128), bufC (32)
    if (gtid < 64) ((uint*)&p.xbf[(size_t)p.N * 128])[gtid] = 0u;
    else if (gtid < 192) ((uint*)&p.bufB[(size_t)p.N * 256])[gtid - 64] = 0u;
    else if (gtid < 224) ((uint*)&p.bufC[(size_t)p.N * 64])[gtid - 192] = 0u;
    // xbf[v][c] = bf16(x[v][c] * normOut[v])
    int nx4 = p.N * 32;
    for (int i4 = gtid; i4 < nx4; i4 += GSZ) {
        int i = i4 * 4;
        int row = i >> 7;
        uint d0 = p.degOut[row];
        float no = d0 ? rsqrtf((float)d0) : 0.f;
        float4 v = *(const float4*)&p.x[i];
        uint2 pkv;
        pkv.x = pk2bf(v.x * no, v.y * no);
        pkv.y = pk2bf(v.z * no, v.w * no);
        *(uint2*)&p.xbf[i] = pkv;
    }
}

// ---------------- pure-sum bucket aggregation, 2-stage pipelined ----------------
template <int V> struct GT;
template <> struct GT<1> { using T = ushort; };
template <> struct GT<2> { using T = uint; };

template <int V>
__device__ __forceinline__ void accum(float* acc, typename GT<V>::T g) {
    if constexpr (V == 1) {
        acc[0] += bfl((uint)g);
    } else {
        acc[0] += bfl(g);
        acc[1] += bfh(g);
    }
}

// SPLIT waves per node (1/2/4); wave `part` owns channels [part*64*V, (part+1)*64*V).
// Block b -> XCD b%8, so b&(SPLIT-1) keeps each XCD on one table slice.
template <int D, int SPLIT, int ACT>
__global__ __launch_bounds__(NTHR) void k_agg(Params p, const ushort* __restrict__ h,
                                              ushort* __restrict__ outb) {
    constexpr int V = D / (64 * SPLIT);
    constexpr int SH = (SPLIT == 4) ? 2 : ((SPLIT == 2) ? 1 : 0);
    using T = typename GT<V>::T;
    int wib = threadIdx.x >> 6;
    int b = blockIdx.x;
    int part = b & (SPLIT - 1);
    int v = (b >> SH) * 4 + wib;
    if (v >= p.N) return;
    int l = threadIdx.x & 63;
    const ushort* hb = h + part * (64 * V) + l * V;
    const ushort* eb = p.ebkt + (size_t)v * CAP;

    int cnt = (int)p.fill[v];
    float nin = p.normIn[v];
    float acc[V] = {};

    if (cnt > 0) {
        int ngrp = (cnt + 7) >> 3;
        ushort8 w = *(const ushort8*)eb;
        T gp[8];
#pragma unroll
        for (int j = 0; j < 8; ++j) gp[j] = *(const T*)&hb[(int)w[j] * D];
        for (int g = 1; g < ngrp; ++g) {
            ushort8 wn = *(const ushort8*)(eb + g * 8);
            T gn[8];
#pragma unroll
            for (int j = 0; j < 8; ++j) gn[j] = *(const T*)&hb[(int)wn[j] * D];
#pragma unroll
            for (int j = 0; j < 8; ++j) accum<V>(acc, gp[j]);
#pragma unroll
            for (int j = 0; j < 8; ++j) gp[j] = gn[j];
        }
#pragma unroll
        for (int j = 0; j < 8; ++j) accum<V>(acc, gp[j]);
    }

    if constexpr (ACT == 0) {
        if constexpr (V == 2) {
            *(uint*)&outb[(size_t)v * D + part * (64 * V) + l * V] =
                pk2bf(acc[0] * nin, acc[1] * nin);
        } else {
            outb[(size_t)v * D + part * 64 + l] = f2bf(acc[0] * nin);
        }
    } else {
        float g = acc[0] * nin + p.b3[l];
        g = 1.f / (1.f + __expf(-g));
        float pa = g * p.Wout[l];
        float pb = g * p.Wout[64 + l];
#pragma unroll
        for (int off = 32; off > 0; off >>= 1) {
            pa += __shfl_down(pa, off);
            pb += __shfl_down(pb, off);
        }
        if (l == 0) {
            p.av[v] = pa;
            p.bv[v] = pb;
        }
    }
}

// ---------------- barrier-free bf16 MFMA GEMM (R9-proven: LDS-staged B panel) ----------
template <int BM, int K, bool RELU, bool BIAS, bool SCALE>
__global__ __launch_bounds__(256) void gemm_nf(const ushort* __restrict__ A,
                                               const ushort* __restrict__ B,
                                               const float* __restrict__ bias,
                                               const float* __restrict__ rowScale,
                                               ushort* __restrict__ C,
                                               int M, int Nn) {
    constexpr int WR = BM / 64;
    constexpr int LB = K + 8;
    __shared__ ushort Bs[64 * LB];

    int tid = threadIdx.x;
    int wave = tid >> 6;
    int lane = tid & 63;
    int l15 = lane & 15;
    int l4 = lane >> 4;
    int m0 = blockIdx.x * BM;
    int n0 = blockIdx.y * 64;

    {
        int j8 = (tid & 7) * 8;
#pragma unroll
        for (int kk = tid >> 3; kk < K; kk += 32) {
            short8 v = *(const short8*)&B[(size_t)kk * Nn + n0 + j8];
#pragma unroll
            for (int j = 0; j < 8; ++j) Bs[(j8 + j) * LB + kk] = (ushort)v[j];
        }
    }
    __syncthreads();

    f32x4 acc[WR][4] = {};
    int rowl[WR];
    const ushort* Ab[WR];
#pragma unroll
    for (int r = 0; r < WR; ++r) {
        rowl[r] = m0 + wave * (16 * WR) + r * 16 + l15;
        Ab[r] = A + (size_t)rowl[r] * K + l4 * 8;
    }

#pragma unroll
    for (int k0 = 0; k0 < K; k0 += 32) {
        short8 bf[4];
#pragma unroll
        for (int n = 0; n < 4; ++n)
            bf[n] = *(const short8*)&Bs[(n * 16 + l15) * LB + k0 + l4 * 8];
#pragma unroll
        for (int r = 0; r < WR; ++r) {
            short8 af = {};
            if (rowl[r] < M) af = *(const short8*)&Ab[r][k0];
#pragma unroll
            for (int n = 0; n < 4; ++n)
                acc[r][n] = __builtin_amdgcn_mfma_f32_16x16x32_bf16(af, bf[n], acc[r][n], 0, 0, 0);
        }
    }

#pragma unroll
    for (int r = 0; r < WR; ++r) {
        int rowb = m0 + wave * (16 * WR) + r * 16 + l4 * 4;
#pragma unroll
        for (int q = 0; q < 4; ++q) {
            int row = rowb + q;
            if (row >= M) continue;
            float sc = SCALE ? rowScale[row] : 1.f;
#pragma unroll
            for (int n = 0; n < 4; ++n) {
                int col = n0 + n * 16 + l15;
                float vv = acc[r][n][q];
                if (BIAS) vv += bias[col];
                if (RELU) vv = fmaxf(vv, 0.f);
                vv *= sc;
                C[(size_t)row * Nn + col] = f2bf(vv);
            }
        }
    }
}

// ---------------- final gather + tanh, 2 pairs/thread ----------------
__global__ __launch_bounds__(NTHR) void k_final(Params p) {
    int i = (blockIdx.x * NTHR + threadIdx.x) * 2;
    float w128 = p.Wout[128];
    float b0 = p.bout[0];
    if (i + 1 < p.P) {
        int2 o2 = *(const int2*)&p.ti[i];
        int2 d2 = *(const int2*)&p.ti[p.P + i];
        float dis0 = p.dis[(size_t)o2.x * p.N + d2.x];
        float dis1 = p.dis[(size_t)o2.y * p.N + d2.y];
        float s0 = p.av[o2.x] + p.bv[d2.x] + dis0 * w128 + b0;
        float s1 = p.av[o2.y] + p.bv[d2.y] + dis1 * w128 + b0;
        float2 r = make_float2(tanhf(s0), tanhf(s1));
        *(float2*)&p.out[i] = r;
    } else if (i < p.P) {
        int o = p.ti[i];
        int d = p.ti[p.P + i];
        float s = p.av[o] + p.bv[d] + p.dis[(size_t)o * p.N + d] * w128 + b0;
        p.out[i] = tanhf(s);
    }
}

extern "C" void kernel_launch(void* const* d_in, const int* in_sizes, int n_in,
                              void* d_out, int out_size, void* d_ws, size_t ws_size,
                              hipStream_t stream) {
    Params prm;
    prm.x    = (const float*)d_in[0];
    prm.dis  = (const float*)d_in[1];
    prm.W1   = (const float*)d_in[2];
    prm.b1   = (const float*)d_in[3];
    prm.W2   = (const float*)d_in[4];
    prm.b2   = (const float*)d_in[5];
    prm.W3   = (const float*)d_in[6];
    prm.b3   = (const float*)d_in[7];
    prm.Wout = (const float*)d_in[8];
    prm.bout = (const float*)d_in[9];
    prm.src  = (const int*)d_in[10];
    prm.dst  = (const int*)d_in[11];
    prm.ti   = (const int*)d_in[12];
    prm.out  = (float*)d_out;

    const int IN = 128, HID = 256, EMB = 64;
    prm.N = in_sizes[0] / IN;
    prm.E = in_sizes[10];
    prm.P = in_sizes[12] / 2;
    const int N = prm.N, E = prm.E, P = prm.P;

    char* ws = (char*)d_ws;
    size_t off = 0;
    auto alloc = [&](size_t bytes) {
        size_t o = off;
        off = (off + bytes + 255) & ~(size_t)255;
        return o;
    };
    size_t o_cnts = alloc((size_t)2 * N * 4);  // degOut | fill
    size_t o_nrmO = alloc((size_t)N * 4);
    size_t o_nrmI = alloc((size_t)N * 4);
    size_t o_ebkt = alloc((size_t)N * CAP * 2);
    size_t o_xbf  = alloc((size_t)(N + 1) * IN * 2);
    size_t o_w1   = alloc((size_t)IN * HID * 2);
    size_t o_w2   = alloc((size_t)HID * HID * 2);
    size_t o_w3   = alloc((size_t)HID * EMB * 2);
    size_t o_bufA = alloc((size_t)N * HID * 2);
    size_t o_bufB = alloc((size_t)(N + 1) * HID * 2);
    size_t o_bufC = alloc((size_t)(N + 1) * EMB * 2);
    size_t o_av   = alloc((size_t)N * 4);
    size_t o_bv   = alloc((size_t)N * 4);
    (void)ws_size;

    prm.degOut  = (uint*)(ws + o_cnts);
    prm.fill    = prm.degOut + N;
    prm.normOut = (float*)(ws + o_nrmO);
    prm.normIn  = (float*)(ws + o_nrmI);
    prm.ebkt    = (ushort*)(ws + o_ebkt);
    prm.xbf     = (ushort*)(ws + o_xbf);
    prm.w1bf    = (ushort*)(ws + o_w1);
    prm.w2bf    = (ushort*)(ws + o_w2);
    prm.w3bf    = (ushort*)(ws + o_w3);
    prm.bufA    = (ushort*)(ws + o_bufA);
    prm.bufB    = (ushort*)(ws + o_bufB);
    prm.bufC    = (ushort*)(ws + o_bufC);
    prm.av      = (float*)(ws + o_av);
    prm.bv      = (float*)(ws + o_bv);

    hipMemsetAsync(prm.degOut, 0, (size_t)2 * N * 4, stream);
    k_deg_scatter<<<(E / 2 + NTHR - 1) / NTHR, NTHR, 0, stream>>>(prm);
    k_norm_cvt<<<512, NTHR, 0, stream>>>(prm);

    int nb4 = (N + 3) / 4;

    // layer1: agg1 (SPLIT=2) -> bufA[N,128] ; gemm1 -> bufB[N,256]
    k_agg<128, 2, 0><<<nb4 * 2, NTHR, 0, stream>>>(prm, prm.xbf, prm.bufA);
    {
        dim3 grid((N + 127) / 128, HID / 64);
        gemm_nf<128, 128, true, true, true><<<grid, 256, 0, stream>>>(
            prm.bufA, prm.w1bf, prm.b1, prm.normOut, prm.bufB, N, HID);
    }
    // layer2: agg2 (SPLIT=4) -> bufA[N,256] ; gemm2 -> bufB[N,256]
    k_agg<256, 4, 0><<<nb4 * 4, NTHR, 0, stream>>>(prm, prm.bufB, prm.bufA);
    {
        dim3 grid((N + 127) / 128, HID / 64);
        gemm_nf<128, 256, true, true, true><<<grid, 256, 0, stream>>>(
            prm.bufA, prm.w2bf, prm.b2, prm.normOut, prm.bufB, N, HID);
    }
    // layer3: gemm3 bufB@W3 -> bufC[N,64] (bufB already carries normOut)
    {
        dim3 grid((N + 63) / 64, EMB / 64);
        gemm_nf<64, 256, false, false, false><<<grid, 256, 0, stream>>>(
            prm.bufB, prm.w3bf, nullptr, nullptr, prm.bufC, N, EMB);
    }
    k_agg<64, 1, 2><<<nb4, NTHR, 0, stream>>>(prm, prm.bufC, nullptr);
    k_final<<<(P / 2 + NTHR - 1) / NTHR, NTHR, 0, stream>>>(prm);
}

// Round 13
// 174.074 us; speedup vs baseline: 1.0982x; 1.0982x over previous
//
#include <hip/hip_runtime.h>
#include <math.h>

typedef __attribute__((ext_vector_type(8))) short short8;
typedef __attribute__((ext_vector_type(8))) unsigned short ushort8;
typedef __attribute__((ext_vector_type(4))) float f32x4;

#define NTHR 256
#define CAP 192  // bucket capacity; max in-degree of Poisson(64) over 10k nodes ~ 110

// ---------- bf16 helpers (RNE) ----------
__device__ __forceinline__ ushort f2bf(float f) {
    uint u = __float_as_uint(f);
    return (ushort)((u + 0x7FFFu + ((u >> 16) & 1u)) >> 16);
}
__device__ __forceinline__ uint pk2bf(float a, float b) {
    return (uint)f2bf(a) | ((uint)f2bf(b) << 16);
}
__device__ __forceinline__ float bfl(uint r) { return __uint_as_float(r << 16); }
__device__ __forceinline__ float bfh(uint r) { return __uint_as_float(r & 0xFFFF0000u); }

struct Params {
    const float* x; const float* dis;
    const float* W1; const float* b1;
    const float* W2; const float* b2;
    const float* W3; const float* b3;
    const float* Wout; const float* bout;
    const int* src; const int* dst; const int* ti;
    float* out;
    uint* degOut; uint* fill;          // fill == in-degree after deg_scatter
    float* normOut; float* normIn;
    ushort* ebkt;                      // [N][CAP] src ids; tail padded to x8 with id N
    ushort* xbf;                       // [N+1][128] pre-scaled by normOut; row N zeros
    ushort* w1bf; ushort* w2bf; ushort* w3bf;  // [K][Nout] row-major bf16
    ushort* bufA;                      // [N][256] agg outputs
    ushort* bufB;                      // [N+1][256] gemm1 out (carries normOut)
    ushort* bufC;                      // [N+1][64]
    float* av; float* bv;
    int N, E, P;
};

// ---------------- k_pre: zero counters + pad rows; convert weights (R9) ----------------
__global__ __launch_bounds__(NTHR) void k_pre(Params p) {
    int gtid = blockIdx.x * NTHR + threadIdx.x;
    int GSZ = gridDim.x * NTHR;
    for (int i = gtid; i < p.N; i += GSZ) {
        p.degOut[i] = 0u;
        p.fill[i] = 0u;
    }
    if (gtid < 64) ((uint*)&p.xbf[(size_t)p.N * 128])[gtid] = 0u;
    else if (gtid < 192) ((uint*)&p.bufB[(size_t)p.N * 256])[gtid - 64] = 0u;
    else if (gtid < 224) ((uint*)&p.bufC[(size_t)p.N * 64])[gtid - 192] = 0u;
    const int n1 = 128 * 256, n2 = 256 * 256, n3 = 256 * 64;
    int nw4 = (n1 + n2 + n3) >> 2;
    for (int i4 = gtid; i4 < nw4; i4 += GSZ) {
        int i = i4 * 4;
        const float* s;
        ushort* d;
        int off;
        if (i < n1) { s = p.W1; d = p.w1bf; off = i; }
        else if (i < n1 + n2) { s = p.W2; d = p.w2bf; off = i - n1; }
        else { s = p.W3; d = p.w3bf; off = i - n1 - n2; }
        float4 v = *(const float4*)&s[off];
        uint2 pkv;
        pkv.x = pk2bf(v.x, v.y);
        pkv.y = pk2bf(v.z, v.w);
        *(uint2*)&d[off] = pkv;
    }
}

// ---------------- k_deg_scatter: one edge pass, 2 edges/thread (R9) ----------------
__global__ __launch_bounds__(NTHR) void k_deg_scatter(Params p) {
    int e = (blockIdx.x * NTHR + threadIdx.x) * 2;
    if (e + 1 < p.E) {
        int2 s2 = *(const int2*)&p.src[e];
        int2 d2 = *(const int2*)&p.dst[e];
        atomicAdd(&p.degOut[s2.x], 1u);
        atomicAdd(&p.degOut[s2.y], 1u);
        uint p0 = atomicAdd(&p.fill[d2.x], 1u);
        p.ebkt[(size_t)d2.x * CAP + p0] = (ushort)s2.x;
        uint p1 = atomicAdd(&p.fill[d2.y], 1u);
        p.ebkt[(size_t)d2.y * CAP + p1] = (ushort)s2.y;
    } else if (e < p.E) {
        int s = p.src[e];
        int v = p.dst[e];
        atomicAdd(&p.degOut[s], 1u);
        uint pos = atomicAdd(&p.fill[v], 1u);
        p.ebkt[(size_t)v * CAP + pos] = (ushort)s;
    }
}

// ------- k_norm_cvt: norms + bucket tail-pad + pre-scaled x cvt (R9) -------
__global__ __launch_bounds__(NTHR) void k_norm_cvt(Params p) {
    int gtid = blockIdx.x * NTHR + threadIdx.x;
    int GSZ = gridDim.x * NTHR;
    for (int v = gtid; v < p.N; v += GSZ) {
        uint d0 = p.degOut[v];
        uint d1 = p.fill[v];
        p.normOut[v] = d0 ? rsqrtf((float)d0) : 0.f;
        p.normIn[v] = d1 ? rsqrtf((float)d1) : 0.f;
        uint c8 = (d1 + 7) & ~7u;
        ushort* eb = p.ebkt + (size_t)v * CAP;
        for (uint j = d1; j < c8; ++j) eb[j] = (ushort)p.N;
    }
    int nx4 = p.N * 32;
    for (int i4 = gtid; i4 < nx4; i4 += GSZ) {
        int i = i4 * 4;
        int row = i >> 7;
        uint d0 = p.degOut[row];
        float no = d0 ? rsqrtf((float)d0) : 0.f;
        float4 v = *(const float4*)&p.x[i];
        uint2 pkv;
        pkv.x = pk2bf(v.x * no, v.y * no);
        pkv.y = pk2bf(v.z * no, v.w * no);
        *(uint2*)&p.xbf[i] = pkv;
    }
}

// ---------------- pure-sum bucket aggregation, 2-stage pipelined (R9) ----------------
template <int V> struct GT;
template <> struct GT<1> { using T = ushort; };
template <> struct GT<2> { using T = uint; };

template <int V>
__device__ __forceinline__ void accum(float* acc, typename GT<V>::T g) {
    if constexpr (V == 1) {
        acc[0] += bfl((uint)g);
    } else {
        acc[0] += bfl(g);
        acc[1] += bfh(g);
    }
}

template <int D, int SPLIT, int ACT>
__global__ __launch_bounds__(NTHR) void k_agg(Params p, const ushort* __restrict__ h,
                                              ushort* __restrict__ outb) {
    constexpr int V = D / (64 * SPLIT);
    using T = typename GT<V>::T;
    int wib = threadIdx.x >> 6;
    int b = blockIdx.x;
    int v, half;
    if constexpr (SPLIT == 2) {
        half = b & 1;  // XCD parity: even/odd XCDs serve disjoint table halves
        v = (b >> 1) * 4 + wib;
    } else {
        half = 0;
        v = b * 4 + wib;
    }
    if (v >= p.N) return;
    int l = threadIdx.x & 63;
    const ushort* hb = h + half * (64 * V) + l * V;
    const ushort* eb = p.ebkt + (size_t)v * CAP;

    int cnt = (int)p.fill[v];
    float nin = p.normIn[v];
    float acc[V] = {};

    if (cnt > 0) {
        int ngrp = (cnt + 7) >> 3;
        ushort8 w = *(const ushort8*)eb;
        T gp[8];
#pragma unroll
        for (int j = 0; j < 8; ++j) gp[j] = *(const T*)&hb[(int)w[j] * D];
        for (int g = 1; g < ngrp; ++g) {
            ushort8 wn = *(const ushort8*)(eb + g * 8);
            T gn[8];
#pragma unroll
            for (int j = 0; j < 8; ++j) gn[j] = *(const T*)&hb[(int)wn[j] * D];
#pragma unroll
            for (int j = 0; j < 8; ++j) accum<V>(acc, gp[j]);
#pragma unroll
            for (int j = 0; j < 8; ++j) gp[j] = gn[j];
        }
#pragma unroll
        for (int j = 0; j < 8; ++j) accum<V>(acc, gp[j]);
    }

    if constexpr (ACT == 0) {
        if constexpr (V == 2) {
            *(uint*)&outb[(size_t)v * D + half * (64 * V) + l * V] =
                pk2bf(acc[0] * nin, acc[1] * nin);
        } else {
            outb[(size_t)v * D + half * 64 + l] = f2bf(acc[0] * nin);
        }
    } else {
        float g = acc[0] * nin + p.b3[l];
        g = 1.f / (1.f + __expf(-g));
        float pa = g * p.Wout[l];
        float pb = g * p.Wout[64 + l];
#pragma unroll
        for (int off = 32; off > 0; off >>= 1) {
            pa += __shfl_down(pa, off);
            pb += __shfl_down(pb, off);
        }
        if (l == 0) {
            p.av[v] = pa;
            p.bv[v] = pb;
        }
    }
}

// ---------------- gemm1 (R9 gemm_nf): LDS-staged B panel, barrier-free K-loop ----------
template <int BM, int K, bool RELU, bool BIAS, bool SCALE>
__global__ __launch_bounds__(256) void gemm_nf(const ushort* __restrict__ A,
                                               const ushort* __restrict__ B,
                                               const float* __restrict__ bias,
                                               const float* __restrict__ rowScale,
                                               ushort* __restrict__ C,
                                               int M, int Nn) {
    constexpr int WR = BM / 64;
    constexpr int LB = K + 8;
    __shared__ ushort Bs[64 * LB];

    int tid = threadIdx.x;
    int wave = tid >> 6;
    int lane = tid & 63;
    int l15 = lane & 15;
    int l4 = lane >> 4;
    int m0 = blockIdx.x * BM;
    int n0 = blockIdx.y * 64;

    {
        int j8 = (tid & 7) * 8;
#pragma unroll
        for (int kk = tid >> 3; kk < K; kk += 32) {
            short8 v = *(const short8*)&B[(size_t)kk * Nn + n0 + j8];
#pragma unroll
            for (int j = 0; j < 8; ++j) Bs[(j8 + j) * LB + kk] = (ushort)v[j];
        }
    }
    __syncthreads();

    f32x4 acc[WR][4] = {};
    int rowl[WR];
    const ushort* Ab[WR];
#pragma unroll
    for (int r = 0; r < WR; ++r) {
        rowl[r] = m0 + wave * (16 * WR) + r * 16 + l15;
        Ab[r] = A + (size_t)rowl[r] * K + l4 * 8;
    }

#pragma unroll
    for (int k0 = 0; k0 < K; k0 += 32) {
        short8 bf[4];
#pragma unroll
        for (int n = 0; n < 4; ++n)
            bf[n] = *(const short8*)&Bs[(n * 16 + l15) * LB + k0 + l4 * 8];
#pragma unroll
        for (int r = 0; r < WR; ++r) {
            short8 af = {};
            if (rowl[r] < M) af = *(const short8*)&Ab[r][k0];
#pragma unroll
            for (int n = 0; n < 4; ++n)
                acc[r][n] = __builtin_amdgcn_mfma_f32_16x16x32_bf16(af, bf[n], acc[r][n], 0, 0, 0);
        }
    }

#pragma unroll
    for (int r = 0; r < WR; ++r) {
        int rowb = m0 + wave * (16 * WR) + r * 16 + l4 * 4;
#pragma unroll
        for (int q = 0; q < 4; ++q) {
            int row = rowb + q;
            if (row >= M) continue;
            float sc = SCALE ? rowScale[row] : 1.f;
#pragma unroll
            for (int n = 0; n < 4; ++n) {
                int col = n0 + n * 16 + l15;
                float vv = acc[r][n][q];
                if (BIAS) vv += bias[col];
                if (RELU) vv = fmaxf(vv, 0.f);
                vv *= sc;
                C[(size_t)row * Nn + col] = f2bf(vv);
            }
        }
    }
}

// ------- k_gemm23: fused gemm2 + gemm3, both with LDS-staged B (R9 staging pattern) -----
// BM=64, 4 waves. gemm2: 4 col-chunks of 64; per chunk stage W2 panel -> Bs, compute
// 64 rows x 64 cols (K=256, A from global bufA), epilogue relu(+b2)*normOut -> Cs (LDS).
// Then stage W3 panel -> Bs, gemm3: bufC = Cs @ W3 (K=256).
__global__ __launch_bounds__(256) void k_gemm23(Params p) {
    constexpr int LB = 264;  // 256 + 8
    __shared__ ushort Bs[64 * LB];
    __shared__ ushort Cs[64 * LB];

    int tid = threadIdx.x;
    int wave = tid >> 6;
    int lane = tid & 63;
    int l15 = lane & 15, l4 = lane >> 4;
    int m0 = blockIdx.x * 64;

    int rowA = m0 + wave * 16 + l15;
    bool rok = rowA < p.N;
    const ushort* Ab = p.bufA + (size_t)rowA * 256 + l4 * 8;

    // ---- gemm2 over 4 column chunks ----
    for (int c = 0; c < 4; ++c) {
        // stage W2 chunk: Bs[col][k] for cols c*64..+63
        {
            int j8 = (tid & 7) * 8;
#pragma unroll
            for (int kk = tid >> 3; kk < 256; kk += 32) {
                short8 v = *(const short8*)&p.w2bf[(size_t)kk * 256 + c * 64 + j8];
#pragma unroll
                for (int j = 0; j < 8; ++j) Bs[(j8 + j) * LB + kk] = (ushort)v[j];
            }
        }
        __syncthreads();

        f32x4 acc[4] = {};
#pragma unroll
        for (int k0 = 0; k0 < 256; k0 += 32) {
            short8 af = {};
            if (rok) af = *(const short8*)&Ab[k0];
#pragma unroll
            for (int n = 0; n < 4; ++n) {
                short8 bf = *(const short8*)&Bs[(n * 16 + l15) * LB + k0 + l4 * 8];
                acc[n] = __builtin_amdgcn_mfma_f32_16x16x32_bf16(af, bf, acc[n], 0, 0, 0);
            }
        }
        // epilogue -> Cs (k-index = global output col)
#pragma unroll
        for (int n = 0; n < 4; ++n) {
            int col = c * 64 + n * 16 + l15;
            float bs = p.b2[col];
#pragma unroll
            for (int q = 0; q < 4; ++q) {
                int rl = wave * 16 + l4 * 4 + q;
                int grow = m0 + rl;
                float no = (grow < p.N) ? p.normOut[grow] : 0.f;
                Cs[rl * LB + col] = f2bf(fmaxf(acc[n][q] + bs, 0.f) * no);
            }
        }
        __syncthreads();
    }

    // ---- stage W3 panel: Bs[col][k], 64 cols x 256 k ----
    {
        int j8 = (tid & 7) * 8;
#pragma unroll
        for (int kk = tid >> 3; kk < 256; kk += 32) {
            short8 v = *(const short8*)&p.w3bf[(size_t)kk * 64 + j8];
#pragma unroll
            for (int j = 0; j < 8; ++j) Bs[(j8 + j) * LB + kk] = (ushort)v[j];
        }
    }
    __syncthreads();

    // ---- gemm3: bufC[64 rows][64 cols] = Cs @ W3, K=256 ----
    {
        f32x4 acc[4] = {};
        const ushort* arow = &Cs[(wave * 16 + l15) * LB + l4 * 8];
#pragma unroll
        for (int k0 = 0; k0 < 256; k0 += 32) {
            short8 af = *(const short8*)&arow[k0];
#pragma unroll
            for (int n = 0; n < 4; ++n) {
                short8 bf = *(const short8*)&Bs[(n * 16 + l15) * LB + k0 + l4 * 8];
                acc[n] = __builtin_amdgcn_mfma_f32_16x16x32_bf16(af, bf, acc[n], 0, 0, 0);
            }
        }
#pragma unroll
        for (int n = 0; n < 4; ++n) {
            int col = n * 16 + l15;
#pragma unroll
            for (int q = 0; q < 4; ++q) {
                int grow = m0 + wave * 16 + l4 * 4 + q;
                if (grow < p.N) p.bufC[(size_t)grow * 64 + col] = f2bf(acc[n][q]);
            }
        }
    }
}

// ---------------- final gather + tanh, 2 pairs/thread (R9) ----------------
__global__ __launch_bounds__(NTHR) void k_final(Params p) {
    int i = (blockIdx.x * NTHR + threadIdx.x) * 2;
    float w128 = p.Wout[128];
    float b0 = p.bout[0];
    if (i + 1 < p.P) {
        int2 o2 = *(const int2*)&p.ti[i];
        int2 d2 = *(const int2*)&p.ti[p.P + i];
        float dis0 = p.dis[(size_t)o2.x * p.N + d2.x];
        float dis1 = p.dis[(size_t)o2.y * p.N + d2.y];
        float s0 = p.av[o2.x] + p.bv[d2.x] + dis0 * w128 + b0;
        float s1 = p.av[o2.y] + p.bv[d2.y] + dis1 * w128 + b0;
        float2 r = make_float2(tanhf(s0), tanhf(s1));
        *(float2*)&p.out[i] = r;
    } else if (i < p.P) {
        int o = p.ti[i];
        int d = p.ti[p.P + i];
        float s = p.av[o] + p.bv[d] + p.dis[(size_t)o * p.N + d] * w128 + b0;
        p.out[i] = tanhf(s);
    }
}

extern "C" void kernel_launch(void* const* d_in, const int* in_sizes, int n_in,
                              void* d_out, int out_size, void* d_ws, size_t ws_size,
                              hipStream_t stream) {
    Params prm;
    prm.x    = (const float*)d_in[0];
    prm.dis  = (const float*)d_in[1];
    prm.W1   = (const float*)d_in[2];
    prm.b1   = (const float*)d_in[3];
    prm.W2   = (const float*)d_in[4];
    prm.b2   = (const float*)d_in[5];
    prm.W3   = (const float*)d_in[6];
    prm.b3   = (const float*)d_in[7];
    prm.Wout = (const float*)d_in[8];
    prm.bout = (const float*)d_in[9];
    prm.src  = (const int*)d_in[10];
    prm.dst  = (const int*)d_in[11];
    prm.ti   = (const int*)d_in[12];
    prm.out  = (float*)d_out;

    const int IN = 128, HID = 256, EMB = 64;
    prm.N = in_sizes[0] / IN;
    prm.E = in_sizes[10];
    prm.P = in_sizes[12] / 2;
    const int N = prm.N, E = prm.E, P = prm.P;

    char* ws = (char*)d_ws;
    size_t off = 0;
    auto alloc = [&](size_t bytes) {
        size_t o = off;
        off = (off + bytes + 255) & ~(size_t)255;
        return o;
    };
    size_t o_cnts = alloc((size_t)2 * N * 4);  // degOut | fill
    size_t o_nrmO = alloc((size_t)N * 4);
    size_t o_nrmI = alloc((size_t)N * 4);
    size_t o_ebkt = alloc((size_t)N * CAP * 2);
    size_t o_xbf  = alloc((size_t)(N + 1) * IN * 2);
    size_t o_w1   = alloc((size_t)IN * HID * 2);
    size_t o_w2   = alloc((size_t)HID * HID * 2);
    size_t o_w3   = alloc((size_t)HID * EMB * 2);
    size_t o_bufA = alloc((size_t)N * HID * 2);
    size_t o_bufB = alloc((size_t)(N + 1) * HID * 2);
    size_t o_bufC = alloc((size_t)(N + 1) * EMB * 2);
    size_t o_av   = alloc((size_t)N * 4);
    size_t o_bv   = alloc((size_t)N * 4);
    (void)ws_size;

    prm.degOut  = (uint*)(ws + o_cnts);
    prm.fill    = prm.degOut + N;
    prm.normOut = (float*)(ws + o_nrmO);
    prm.normIn  = (float*)(ws + o_nrmI);
    prm.ebkt    = (ushort*)(ws + o_ebkt);
    prm.xbf     = (ushort*)(ws + o_xbf);
    prm.w1bf    = (ushort*)(ws + o_w1);
    prm.w2bf    = (ushort*)(ws + o_w2);
    prm.w3bf    = (ushort*)(ws + o_w3);
    prm.bufA    = (ushort*)(ws + o_bufA);
    prm.bufB    = (ushort*)(ws + o_bufB);
    prm.bufC    = (ushort*)(ws + o_bufC);
    prm.av      = (float*)(ws + o_av);
    prm.bv      = (float*)(ws + o_bv);

    k_pre<<<256, NTHR, 0, stream>>>(prm);
    k_deg_scatter<<<(E / 2 + NTHR - 1) / NTHR, NTHR, 0, stream>>>(prm);
    k_norm_cvt<<<1024, NTHR, 0, stream>>>(prm);

    int nb4 = (N + 3) / 4;

    // layer1: agg1 (SPLIT=1) -> bufA[N,128] ; gemm1 -> bufB[N,256]
    k_agg<128, 1, 0><<<nb4, NTHR, 0, stream>>>(prm, prm.xbf, prm.bufA);
    {
        dim3 grid((N + 127) / 128, HID / 64);
        gemm_nf<128, 128, true, true, true><<<grid, 256, 0, stream>>>(
            prm.bufA, prm.w1bf, prm.b1, prm.normOut, prm.bufB, N, HID);
    }
    // layer2+3: agg2 (SPLIT=2) -> bufA[N,256] ; fused gemm2+gemm3 -> bufC[N,64]
    k_agg<256, 2, 0><<<nb4 * 2, NTHR, 0, stream>>>(prm, prm.bufB, prm.bufA);
    k_gemm23<<<(N + 63) / 64, 256, 0, stream>>>(prm);
    // layer3 agg + sigmoid + Wout dots
    k_agg<64, 1, 2><<<nb4, NTHR, 0, stream>>>(prm, prm.bufC, nullptr);
    k_final<<<(P / 2 + NTHR - 1) / NTHR, NTHR, 0, stream>>>(prm);
}

// Round 14
// 164.649 us; speedup vs baseline: 1.1610x; 1.0572x over previous
//
#include <hip/hip_runtime.h>
#include <math.h>

typedef __attribute__((ext_vector_type(8))) short short8;
typedef __attribute__((ext_vector_type(8))) unsigned short ushort8;
typedef __attribute__((ext_vector_type(4))) float f32x4;

#define NTHR 256
#define CAP 192  // bucket capacity per node; max in-degree of Poisson(64) over 10k nodes ~ 110

// ---------- bf16 helpers (RNE) ----------
__device__ __forceinline__ ushort f2bf(float f) {
    uint u = __float_as_uint(f);
    return (ushort)((u + 0x7FFFu + ((u >> 16) & 1u)) >> 16);
}
__device__ __forceinline__ uint pk2bf(float a, float b) {
    return (uint)f2bf(a) | ((uint)f2bf(b) << 16);
}
__device__ __forceinline__ float bfl(uint r) { return __uint_as_float(r << 16); }
__device__ __forceinline__ float bfh(uint r) { return __uint_as_float(r & 0xFFFF0000u); }

struct Params {
    const float* x; const float* dis;
    const float* W1; const float* b1;
    const float* W2; const float* b2;
    const float* W3; const float* b3;
    const float* Wout; const float* bout;
    const int* src; const int* dst; const int* ti;
    float* out;
    uint* degOut; uint* fill;          // fill == in-degree after deg_scatter
    float* normOut; float* normIn;
    ushort* ebkt;                      // [N][CAP] src ids, pads = N (zero row)
    ushort* xbf; ushort* w1bf; ushort* w2bf; ushort* w3bf;
    ushort* bufA; ushort* bufB; ushort* bufC;
    float* av; float* bv;
    int N, E, P;
};

// ---------------- k_pre: zero counters, fill buckets with pad id N, zero rows N -------
__global__ __launch_bounds__(NTHR) void k_pre(Params p) {
    int gtid = blockIdx.x * NTHR + threadIdx.x;
    int GSZ = gridDim.x * NTHR;
    for (int i = gtid; i < p.N; i += GSZ) {
        p.degOut[i] = 0u;
        p.fill[i] = 0u;
    }
    uint pat = (uint)p.N | ((uint)p.N << 16);
    uint* eb = (uint*)p.ebkt;
    int nE2 = p.N * (CAP / 2);
    for (int i = gtid; i < nE2; i += GSZ) eb[i] = pat;
    // zero rows N (the pad target row) of xbf[*,128], bufB[*,256], bufC[*,64]
    if (gtid < 64) ((uint*)&p.xbf[(size_t)p.N * 128])[gtid & 31] = 0u;
    if (gtid >= 64 && gtid < 128) ((uint*)&p.bufC[(size_t)p.N * 64])[gtid & 15] = 0u;
    if (gtid >= 128 && gtid < 192) ((uint*)&p.bufB[(size_t)p.N * 256])[gtid & 63] = 0u;
}

// ---------------- k_deg_scatter: ONE edge pass: out-degree + bucket scatter ----------
__global__ __launch_bounds__(NTHR) void k_deg_scatter(Params p) {
    int e = blockIdx.x * NTHR + threadIdx.x;
    if (e < p.E) {
        int s = p.src[e];
        int v = p.dst[e];
        atomicAdd(&p.degOut[s], 1u);
        uint pos = atomicAdd(&p.fill[v], 1u);
        p.ebkt[(size_t)v * CAP + pos] = (ushort)s;
    }
}

// ---------------- k_norm_cvt: norms + pre-scaled x cvt + weight cvt ----------------
__global__ __launch_bounds__(NTHR) void k_norm_cvt(Params p) {
    int gtid = blockIdx.x * NTHR + threadIdx.x;
    int GSZ = gridDim.x * NTHR;
    // norms
    for (int v = gtid; v < p.N; v += GSZ) {
        uint d0 = p.degOut[v];
        uint d1 = p.fill[v];
        p.normOut[v] = d0 ? rsqrtf((float)d0) : 0.f;
        p.normIn[v] = d1 ? rsqrtf((float)d1) : 0.f;
    }
    // xbf[v][c] = bf16(x[v][c] * normOut[v])
    int nx4 = p.N * 32;  // N*128/4
    for (int i4 = gtid; i4 < nx4; i4 += GSZ) {
        int i = i4 * 4;
        int row = i >> 7;
        uint d0 = p.degOut[row];
        float no = d0 ? rsqrtf((float)d0) : 0.f;
        float4 v = *(const float4*)&p.x[i];
        uint2 pkv;
        pkv.x = pk2bf(v.x * no, v.y * no);
        pkv.y = pk2bf(v.z * no, v.w * no);
        *(uint2*)&p.xbf[i] = pkv;
    }
    // weights (unscaled)
    const int n1 = 128 * 256, n2 = 256 * 256, n3 = 256 * 64;
    int nw4 = (n1 + n2 + n3) >> 2;
    for (int i4 = gtid; i4 < nw4; i4 += GSZ) {
        int i = i4 * 4;
        const float* s;
        ushort* d;
        int off;
        if (i < n1) { s = p.W1; d = p.w1bf; off = i; }
        else if (i < n1 + n2) { s = p.W2; d = p.w2bf; off = i - n1; }
        else { s = p.W3; d = p.w3bf; off = i - n1 - n2; }
        float4 v = *(const float4*)&s[off];
        uint2 pkv;
        pkv.x = pk2bf(v.x, v.y);
        pkv.y = pk2bf(v.z, v.w);
        *(uint2*)&d[off] = pkv;
    }
}

// ---------------- pure-sum bucket aggregation ----------------
template <int V> struct GT;
template <> struct GT<1> { using T = ushort; };
template <> struct GT<2> { using T = uint; };

template <int V>
__device__ __forceinline__ void accum(float* acc, typename GT<V>::T g) {
    if constexpr (V == 1) {
        acc[0] += bfl((uint)g);
    } else {
        acc[0] += bfl(g);
        acc[1] += bfh(g);
    }
}

// SPLIT waves per node; wave `half` owns channels [half*64*V, (half+1)*64*V).
// Buckets padded to groups of 8 with src=N -> zero row.
// ACT==0: outb[v][..] = bf16(normIn[v] * sum)
// ACT==2: g = sigmoid(sum*normIn + b3[l]); av[v]=g.WoutA, bv[v]=g.WoutB
template <int D, int SPLIT, int ACT>
__global__ __launch_bounds__(NTHR) void k_agg(Params p, const ushort* __restrict__ h,
                                              ushort* __restrict__ outb) {
    constexpr int V = D / (64 * SPLIT);
    using T = typename GT<V>::T;
    int wib = threadIdx.x >> 6;
    int b = blockIdx.x;
    int v, half;
    if constexpr (SPLIT == 2) {
        half = b & 1;  // XCD parity: even/odd XCDs serve disjoint table halves
        v = (b >> 1) * 4 + wib;
    } else {
        half = 0;
        v = b * 4 + wib;
    }
    if (v >= p.N) return;
    int l = threadIdx.x & 63;
    const ushort* hb = h + half * (64 * V) + l * V;
    const ushort* eb = p.ebkt + (size_t)v * CAP;

    int cnt = (int)p.fill[v];
    float acc[V] = {};

    if (cnt > 0) {
        int ngrp = (cnt + 7) >> 3;
        ushort8 w = *(const ushort8*)eb;
        int g = 0;
        for (;;) {
            T gg[8];
#pragma unroll
            for (int j = 0; j < 8; ++j) gg[j] = *(const T*)&hb[(int)w[j] * D];
            ++g;
            bool more = g < ngrp;
            ushort8 wn;
            if (more) wn = *(const ushort8*)(eb + g * 8);
#pragma unroll
            for (int j = 0; j < 8; ++j) accum<V>(acc, gg[j]);
            if (!more) break;
            w = wn;
        }
    }

    float nin = p.normIn[v];
    if constexpr (ACT == 0) {
        static_assert(V == 2, "ACT0 expects V==2");
        *(uint*)&outb[(size_t)v * D + half * (64 * V) + l * V] =
            pk2bf(acc[0] * nin, acc[1] * nin);
    } else {
        float g = acc[0] * nin + p.b3[l];
        g = 1.f / (1.f + __expf(-g));
        float pa = g * p.Wout[l];
        float pb = g * p.Wout[64 + l];
#pragma unroll
        for (int off = 32; off > 0; off >>= 1) {
            pa += __shfl_down(pa, off);
            pb += __shfl_down(pb, off);
        }
        if (l == 0) {
            p.av[v] = pa;
            p.bv[v] = pb;
        }
    }
}

// ---------------- barrier-free bf16 MFMA GEMM with optional normOut epilogue scale ----
// C[M,Nn] = scale(row) * act(A[M,K] @ B[K,Nn] + bias)
template <int BM, int K, bool RELU, bool BIAS, bool SCALE>
__global__ __launch_bounds__(256) void gemm_nf(const ushort* __restrict__ A,
                                               const ushort* __restrict__ B,
                                               const float* __restrict__ bias,
                                               const float* __restrict__ rowScale,
                                               ushort* __restrict__ C,
                                               int M, int Nn) {
    constexpr int WR = BM / 64;
    constexpr int LB = K + 8;
    __shared__ ushort Bs[64 * LB];

    int tid = threadIdx.x;
    int wave = tid >> 6;
    int lane = tid & 63;
    int l15 = lane & 15;
    int l4 = lane >> 4;
    int m0 = blockIdx.x * BM;
    int n0 = blockIdx.y * 64;

    {
        int j8 = (tid & 7) * 8;
#pragma unroll
        for (int kk = tid >> 3; kk < K; kk += 32) {
            short8 v = *(const short8*)&B[(size_t)kk * Nn + n0 + j8];
#pragma unroll
            for (int j = 0; j < 8; ++j) Bs[(j8 + j) * LB + kk] = (ushort)v[j];
        }
    }
    __syncthreads();

    f32x4 acc[WR][4] = {};
    int rowl[WR];
    const ushort* Ab[WR];
#pragma unroll
    for (int r = 0; r < WR; ++r) {
        rowl[r] = m0 + wave * (16 * WR) + r * 16 + l15;
        Ab[r] = A + (size_t)rowl[r] * K + l4 * 8;
    }

#pragma unroll
    for (int k0 = 0; k0 < K; k0 += 32) {
        short8 bf[4];
#pragma unroll
        for (int n = 0; n < 4; ++n)
            bf[n] = *(const short8*)&Bs[(n * 16 + l15) * LB + k0 + l4 * 8];
#pragma unroll
        for (int r = 0; r < WR; ++r) {
            short8 af = {};
            if (rowl[r] < M) af = *(const short8*)&Ab[r][k0];
#pragma unroll
            for (int n = 0; n < 4; ++n)
                acc[r][n] = __builtin_amdgcn_mfma_f32_16x16x32_bf16(af, bf[n], acc[r][n], 0, 0, 0);
        }
    }

#pragma unroll
    for (int r = 0; r < WR; ++r) {
        int rowb = m0 + wave * (16 * WR) + r * 16 + l4 * 4;
#pragma unroll
        for (int q = 0; q < 4; ++q) {
            int row = rowb + q;
            if (row >= M) continue;
            float sc = SCALE ? rowScale[row] : 1.f;
#pragma unroll
            for (int n = 0; n < 4; ++n) {
                int col = n0 + n * 16 + l15;
                float vv = acc[r][n][q];
                if (BIAS) vv += bias[col];
                if (RELU) vv = fmaxf(vv, 0.f);
                vv *= sc;
                C[(size_t)row * Nn + col] = f2bf(vv);
            }
        }
    }
}

// ---------------- final gather + tanh ----------------
__global__ __launch_bounds__(NTHR) void k_final(Params p) {
    int i = blockIdx.x * NTHR + threadIdx.x;
    if (i >= p.P) return;
    int o = p.ti[i];
    int d = p.ti[p.P + i];
    float s = p.av[o] + p.bv[d] + p.dis[(size_t)o * p.N + d] * p.Wout[128] + p.bout[0];
    p.out[i] = tanhf(s);
}

extern "C" void kernel_launch(void* const* d_in, const int* in_sizes, int n_in,
                              void* d_out, int out_size, void* d_ws, size_t ws_size,
                              hipStream_t stream) {
    Params prm;
    prm.x    = (const float*)d_in[0];
    prm.dis  = (const float*)d_in[1];
    prm.W1   = (const float*)d_in[2];
    prm.b1   = (const float*)d_in[3];
    prm.W2   = (const float*)d_in[4];
    prm.b2   = (const float*)d_in[5];
    prm.W3   = (const float*)d_in[6];
    prm.b3   = (const float*)d_in[7];
    prm.Wout = (const float*)d_in[8];
    prm.bout = (const float*)d_in[9];
    prm.src  = (const int*)d_in[10];
    prm.dst  = (const int*)d_in[11];
    prm.ti   = (const int*)d_in[12];
    prm.out  = (float*)d_out;

    const int IN = 128, HID = 256, EMB = 64;
    prm.N = in_sizes[0] / IN;
    prm.E = in_sizes[10];
    prm.P = in_sizes[12] / 2;
    const int N = prm.N, E = prm.E, P = prm.P;

    char* ws = (char*)d_ws;
    size_t off = 0;
    auto alloc = [&](size_t bytes) {
        size_t o = off;
        off = (off + bytes + 255) & ~(size_t)255;
        return o;
    };
    size_t o_degO = alloc((size_t)N * 4);
    size_t o_fill = alloc((size_t)N * 4);
    size_t o_nrmO = alloc((size_t)N * 4);
    size_t o_nrmI = alloc((size_t)N * 4);
    size_t o_ebkt = alloc((size_t)N * CAP * 2);
    size_t o_xbf  = alloc((size_t)(N + 1) * IN * 2);
    size_t o_w1   = alloc((size_t)IN * HID * 2);
    size_t o_w2   = alloc((size_t)HID * HID * 2);
    size_t o_w3   = alloc((size_t)HID * EMB * 2);
    size_t o_bufA = alloc((size_t)N * HID * 2);
    size_t o_bufB = alloc((size_t)(N + 1) * HID * 2);
    size_t o_bufC = alloc((size_t)(N + 1) * EMB * 2);
    size_t o_av   = alloc((size_t)N * 4);
    size_t o_bv   = alloc((size_t)N * 4);
    (void)ws_size;

    prm.degOut  = (uint*)(ws + o_degO);
    prm.fill    = (uint*)(ws + o_fill);
    prm.normOut = (float*)(ws + o_nrmO);
    prm.normIn  = (float*)(ws + o_nrmI);
    prm.ebkt    = (ushort*)(ws + o_ebkt);
    prm.xbf     = (ushort*)(ws + o_xbf);
    prm.w1bf    = (ushort*)(ws + o_w1);
    prm.w2bf    = (ushort*)(ws + o_w2);
    prm.w3bf    = (ushort*)(ws + o_w3);
    prm.bufA    = (ushort*)(ws + o_bufA);
    prm.bufB    = (ushort*)(ws + o_bufB);
    prm.bufC    = (ushort*)(ws + o_bufC);
    prm.av      = (float*)(ws + o_av);
    prm.bv      = (float*)(ws + o_bv);

    k_pre<<<1024, NTHR, 0, stream>>>(prm);
    k_deg_scatter<<<(E + NTHR - 1) / NTHR, NTHR, 0, stream>>>(prm);
    k_norm_cvt<<<1024, NTHR, 0, stream>>>(prm);

    int nb4 = (N + 3) / 4;

    // layer1: agg(xbf) -> bufA[N,128] ; gemm K=128 (+b1, relu, *normOut) -> bufB[N,256]
    k_agg<128, 1, 0><<<nb4, NTHR, 0, stream>>>(prm, prm.xbf, prm.bufA);
    {
        dim3 grid((N + 127) / 128, HID / 64);
        gemm_nf<128, 128, true, true, true><<<grid, 256, 0, stream>>>(
            prm.bufA, prm.w1bf, prm.b1, prm.normOut, prm.bufB, N, HID);
    }
    // layer2: agg(bufB) -> bufA[N,256] ; gemm K=256 (+b2, relu, *normOut) -> bufB[N,256]
    k_agg<256, 2, 0><<<nb4 * 2, NTHR, 0, stream>>>(prm, prm.bufB, prm.bufA);
    {
        dim3 grid((N + 127) / 128, HID / 64);
        gemm_nf<128, 256, true, true, true><<<grid, 256, 0, stream>>>(
            prm.bufA, prm.w2bf, prm.b2, prm.normOut, prm.bufB, N, HID);
    }
    // layer3 reordered: bufC = bufB @ W3 (bufB already carries normOut; no extra scale)
    {
        dim3 grid((N + 63) / 64, EMB / 64);
        gemm_nf<64, 256, false, false, false><<<grid, 256, 0, stream>>>(
            prm.bufB, prm.w3bf, nullptr, nullptr, prm.bufC, N, EMB);
    }
    k_agg<64, 1, 2><<<nb4, NTHR, 0, stream>>>(prm, prm.bufC, nullptr);
    k_final<<<(P + NTHR - 1) / NTHR, NTHR, 0, stream>>>(prm);
}